// Round 3
// baseline (47.050 us; speedup 1.0000x reference)
//
#include <hip/hip_runtime.h>

typedef __bf16 bf16x8 __attribute__((ext_vector_type(8)));
typedef float  f32x4  __attribute__((ext_vector_type(4)));

#define D100 100
#define NPAD 112                   // padded col count (7*16)
#define NROWS (4096*64)            // 262144 rows of X
#define NTILES (NROWS/16)          // 16384 16-row tiles
#define NCT 7                      // col tiles: 7*16 = 112 >= 100
#define NKS 4                      // k steps:  4*32 = 128 >= 100
#define FRAG_ELEMS (NCT*NKS*64*8)  // 14336 bf16 fragment elements (28672 B)
#define NBLK (NTILES/4)            // 4096 blocks, 4 waves each, 1 tile/wave

// ---------------------------------------------------------------------------
// Kernel 1: build M = W^T * S in MFMA fragment order (bf16, zero-padded) and
// c = b * S (fp32, zero-padded to 112). M[k][n] = sum_d W[d*100+k]*S[d*100+n].
// Fragment order: wsM[((ct*4+ks)*64 + lane)*8 + j] holds
//   M[ ks*32 + (lane>>4)*8 + j ][ ct*16 + (lane&15) ]
// ---------------------------------------------------------------------------
__global__ __launch_bounds__(256) void prep_kernel(
    const float* __restrict__ W, const float* __restrict__ bvec,
    const float* __restrict__ S, __bf16* __restrict__ wsM,
    float* __restrict__ wsc) {
  int tid = blockIdx.x * 256 + threadIdx.x;
  if (tid < FRAG_ELEMS) {
    int j    = tid & 7;
    int lane = (tid >> 3) & 63;
    int ks   = (tid >> 9) & 3;
    int ct   = tid >> 11;
    int k = ks * 32 + ((lane >> 4) * 8) + j;
    int n = ct * 16 + (lane & 15);
    float acc = 0.f;
    if (k < D100 && n < D100) {
      float a0 = 0.f, a1 = 0.f, a2 = 0.f, a3 = 0.f;
      for (int d = 0; d < D100; d += 4) {
        a0 += W[(d + 0) * D100 + k] * S[(d + 0) * D100 + n];
        a1 += W[(d + 1) * D100 + k] * S[(d + 1) * D100 + n];
        a2 += W[(d + 2) * D100 + k] * S[(d + 2) * D100 + n];
        a3 += W[(d + 3) * D100 + k] * S[(d + 3) * D100 + n];
      }
      acc = (a0 + a1) + (a2 + a3);
    }
    wsM[tid] = (__bf16)acc;
  } else if (tid < FRAG_ELEMS + 128) {
    int n = tid - FRAG_ELEMS;
    if (n < NPAD) {
      float a = 0.f;
      if (n < D100)
        for (int d = 0; d < D100; ++d) a += bvec[d] * S[d * D100 + n];
      wsc[n] = a;  // zero for 100..111
    }
  }
}

// ---------------------------------------------------------------------------
// Kernel 2: out[r][n] = sum_k x[r][k] * M[k][n] + c[n]
// 4 waves/block, ONE 16-row tile per wave. SWAPPED operands:
//   D = M^T-tile (A op) * x^T-tile (B op)  ->  D[row=n][col=r]
// so lane (l16=r, lg) reg q holds out[r][ct*16 + lg*4 + q]: direct f32x4
// stores, no LDS transpose, no second barrier. LDS = B fragments only
// (28.7 KB -> 5 blocks/CU).
// ---------------------------------------------------------------------------
__global__ __launch_bounds__(256) void gemm_kernel(
    const float* __restrict__ x, const __bf16* __restrict__ wsM,
    const float* __restrict__ wsc, float* __restrict__ out) {
  __shared__ __align__(16) __bf16 ldsB[FRAG_ELEMS];  // 28672 B

  const int t    = threadIdx.x;
  const int lane = t & 63;
  const int l16  = lane & 15;
  const int lg   = lane >> 4;
  const int tile = blockIdx.x * 4 + (t >> 6);

  // --- stage M fragments into LDS: 1792 x 16B chunks, 7 per thread ---
  {
    const f32x4* src = (const f32x4*)wsM;
    f32x4*       dst = (f32x4*)ldsB;
#pragma unroll
    for (int i = 0; i < 7; ++i) dst[i * 256 + t] = src[i * 256 + t];
  }

  // --- issue all x loads up front (7 x f32x4 per lane) ---
  const float* xr = x + (size_t)tile * (16 * D100) + l16 * D100;
  f32x4 xv[7];
#pragma unroll
  for (int ks = 0; ks < 3; ++ks) {
    xv[ks * 2]     = *(const f32x4*)(xr + ks * 32 + lg * 8);
    xv[ks * 2 + 1] = *(const f32x4*)(xr + ks * 32 + lg * 8 + 4);
  }
  xv[6] = (lg == 0) ? *(const f32x4*)(xr + 96) : (f32x4){0.f, 0.f, 0.f, 0.f};

  // --- bias: acc[ct][q] = c[ct*16 + lg*4 + q]  (wsc zero-padded to 112) ---
  const f32x4* cv = (const f32x4*)wsc;
  f32x4 acc[NCT];
#pragma unroll
  for (int ct = 0; ct < NCT; ++ct) acc[ct] = cv[ct * 4 + lg];

  __syncthreads();  // ldsB ready

  const bf16x8* Bv = (const bf16x8*)ldsB;
#pragma unroll
  for (int ks = 0; ks < NKS; ++ks) {
    bf16x8 xf;
    if (ks < 3) {
      f32x4 v0 = xv[ks * 2], v1 = xv[ks * 2 + 1];
#pragma unroll
      for (int j = 0; j < 4; ++j) {
        xf[j]     = (__bf16)v0[j];
        xf[j + 4] = (__bf16)v1[j];
      }
    } else {
      f32x4 v0 = xv[6];  // zero for lg != 0
#pragma unroll
      for (int j = 0; j < 4; ++j) {
        xf[j]     = (__bf16)v0[j];
        xf[j + 4] = (__bf16)0.f;
      }
    }
#pragma unroll
    for (int ct = 0; ct < NCT; ++ct)
      acc[ct] = __builtin_amdgcn_mfma_f32_16x16x32_bf16(
          Bv[(ct * NKS + ks) * 64 + lane], xf, acc[ct], 0, 0, 0);
  }

  // --- direct aligned f32x4 stores: lane owns out[r][ct*16+lg*4 .. +3] ---
  float* orow = out + (size_t)tile * (16 * D100) + l16 * D100 + lg * 4;
#pragma unroll
  for (int ct = 0; ct < NCT; ++ct) {
    if (ct < 6 || lg == 0)  // cols 100..111 don't exist
      *(f32x4*)(orow + ct * 16) = acc[ct];
  }
}

extern "C" void kernel_launch(void* const* d_in, const int* in_sizes, int n_in,
                              void* d_out, int out_size, void* d_ws,
                              size_t ws_size, hipStream_t stream) {
  const float* x = (const float*)d_in[0];
  const float* W = (const float*)d_in[1];
  const float* b = (const float*)d_in[2];
  const float* S = (const float*)d_in[3];
  __bf16* wsM = (__bf16*)d_ws;
  float*  wsc = (float*)((char*)d_ws + (size_t)FRAG_ELEMS * 2);
  float*  out = (float*)d_out;

  hipLaunchKernelGGL(prep_kernel, dim3(57), dim3(256), 0, stream,
                     W, b, S, wsM, wsc);
  hipLaunchKernelGGL(gemm_kernel, dim3(NBLK), dim3(256), 0, stream,
                     x, wsM, wsc, out);
}